// Round 5
// baseline (1511.976 us; speedup 1.0000x reference)
//
#include <hip/hip_runtime.h>
#include <math.h>

// FineGrainLoss: B=96, n1=196 (image tokens), n2=77 (text tokens), d=512.
#define BB 96
#define N1 196
#define N2 77
#define DD 512

#define MT 13   // M tiles of 16 (208 rows, 196 valid)
#define NT 5    // N tiles of 16 (80 cols, 77 valid)

#define IMGN (BB * N1 * DD)
#define TXTN (BB * N2 * DD)

// BK=64 staging: 36 tiles of 64 cells (16 B each = 8 f16 frag slice).
// Tile map: T in [0,36): sub = T/18; T'=T%18; T'<13 -> A strip T'; else B ct T'-13.
#define TILES 36
#define CELLS (TILES * 64)   // 2304 = 9*256

typedef _Float16 f16x8 __attribute__((ext_vector_type(8)));  // 8 f16 (4 VGPR)
typedef float f4v __attribute__((ext_vector_type(4)));       // MFMA C/D

typedef unsigned int __attribute__((address_space(1))) as1_uint;
typedef unsigned int __attribute__((address_space(3))) as3_uint;

__device__ __forceinline__ void gload_lds16(const void* g, void* l) {
    __builtin_amdgcn_global_load_lds((const as1_uint*)g, (as3_uint*)l, 16, 0, 0);
}

// fp32 -> fp16 convert pass (4 elems/thread).
__global__ void convert_kernel(const float* __restrict__ src,
                               _Float16* __restrict__ dst, int n) {
    int i = (blockIdx.x * blockDim.x + threadIdx.x) * 4;
    if (i >= n) return;
    float4 v = *(const float4*)(src + i);
    union { _Float16 h[4]; ushort2 u2[2]; uint2 u; } o;
    o.h[0] = (_Float16)v.x; o.h[1] = (_Float16)v.y;
    o.h[2] = (_Float16)v.z; o.h[3] = (_Float16)v.w;
    *(uint2*)(dst + i) = o.u;
}

// One K=32 sub-step for wave units [U0,U1), strip-major u = strip*NT + ct.
template <int U0, int U1>
__device__ __forceinline__ void compute_sub(const f16x8* __restrict__ fr,
                                            f4v* __restrict__ acc, int lane) {
    constexpr int S0 = U0 / NT, S1 = (U1 - 1) / NT, NS = S1 - S0 + 1;
    f16x8 bh[NT];
#pragma unroll
    for (int ct = 0; ct < NT; ++ct) bh[ct] = fr[(13 + ct) * 64 + lane];
#pragma unroll
    for (int i = 0; i < NS; ++i) {
        const int s = S0 + i;
        f16x8 ah = fr[s * 64 + lane];
#pragma unroll
        for (int ct = 0; ct < NT; ++ct) {
            const int u = s * NT + ct;
            if (u >= U0 && u < U1)
                acc[u - U0] = __builtin_amdgcn_mfma_f32_16x16x32_f16(
                    ah, bh[ct], acc[u - U0], 0, 0, 0);
        }
    }
}

// Per-wave reduction partials. C/D layout: col = lane&15, row = (lane>>4)*4+reg.
// rp: [13 strips][4 waves][16 rows], cp: [80 cols][4 waves].
template <int U0, int U1>
__device__ __forceinline__ void reduce_phase1(const f4v* __restrict__ acc, int wave,
                                              int lq, int lm,
                                              float* __restrict__ rp,
                                              float* __restrict__ cp) {
    constexpr int S0 = U0 / NT, S1 = (U1 - 1) / NT, NS = S1 - S0 + 1;
    float colm[NT];
#pragma unroll
    for (int ct = 0; ct < NT; ++ct) colm[ct] = -INFINITY;
    float rowm[NS][4];
#pragma unroll
    for (int i = 0; i < NS; ++i)
#pragma unroll
        for (int r = 0; r < 4; ++r) rowm[i][r] = -INFINITY;

#pragma unroll
    for (int u = U0; u < U1; ++u) {
        const int s = u / NT, ct = u % NT;
        f4v a = acc[u - U0];
        bool rows_ok = (s != MT - 1) || (lq == 0);        // rows >=196 invalid
        float cm = fmaxf(fmaxf(a[0], a[1]), fmaxf(a[2], a[3]));
        colm[ct] = fmaxf(colm[ct], rows_ok ? cm : -INFINITY);
        bool col_ok = (ct != NT - 1) || (lm < N2 - 64);   // cols >=77 invalid
#pragma unroll
        for (int r = 0; r < 4; ++r)
            rowm[s - S0][r] = fmaxf(rowm[s - S0][r], col_ok ? a[r] : -INFINITY);
    }
#pragma unroll
    for (int ct = 0; ct < NT; ++ct) {
        float m = colm[ct];
        m = fmaxf(m, __shfl_xor(m, 16));
        m = fmaxf(m, __shfl_xor(m, 32));
        if (lq == 0) cp[(ct * 16 + lm) * 4 + wave] = m;
    }
#pragma unroll
    for (int i = 0; i < NS; ++i) {
#pragma unroll
        for (int r = 0; r < 4; ++r) {
            float m = rowm[i][r];
            m = fmaxf(m, __shfl_xor(m, 1));
            m = fmaxf(m, __shfl_xor(m, 2));
            m = fmaxf(m, __shfl_xor(m, 4));
            m = fmaxf(m, __shfl_xor(m, 8));
            if (lm == 0) rp[(S0 + i) * 64 + wave * 16 + lq * 4 + r] = m;
        }
    }
}

// One block per (bi, bt): S[208x80] = img[bi].txt[bt]^T, single f16 MFMA,
// BK=64 global_load_lds staging (m97 structure), fused max/mean epilogue.
// PRE=false: stage from fp32 with in-kernel f16 convert (ws too small).
template <bool PRE>
__global__ __launch_bounds__(256, 4) void sim_mfma_kernel(
    const float* __restrict__ imgF, const float* __restrict__ txtF,
    const _Float16* __restrict__ h16,   // [img | txt] concatenated
    float* __restrict__ i2t, float* __restrict__ t2i)
{
    const int bt = blockIdx.x, bi = blockIdx.y;
    const int tid = threadIdx.x;
    const int wave = tid >> 6, lane = tid & 63;
    const int lm = lane & 15;
    const int lq = lane >> 4;

    __shared__ __align__(16) _Float16 lds[CELLS * 8];   // 36,864 B
    // epilogue scratch aliases the staging tile (K loop fully done first)
    float* rp  = (float*)lds;          // 832: [strip][wave][16]
    float* cp  = (float*)lds + 832;    // 320: [col][wave]
    float* sws = (float*)lds + 1152;   // 8

    // ---- per-thread staging descriptors (k-invariant element offsets) ----
    // Thread stages cells of tile T = 4j + wave, cell-in-tile = lane.
    int off[9];
    const float* fsrc[9];
#pragma unroll
    for (int j = 0; j < 9; ++j) {
        const int T = 4 * j + wave;
        const int sub = T / 18, Tp = T % 18;
        const int kb = lq;   // k-block within K32: lane>>4
        int o;
        bool isA = (Tp < 13);
        if (isA) {
            int q = Tp * 16 + lm; q = q > (N1 - 1) ? (N1 - 1) : q;
            o = (bi * N1 + q) * DD + sub * 32 + kb * 8;
        } else {
            int r = (Tp - 13) * 16 + lm; r = r > (N2 - 1) ? (N2 - 1) : r;
            o = (bt * N2 + r) * DD + sub * 32 + kb * 8;
        }
        if constexpr (PRE) {
            off[j] = isA ? o : (IMGN + o);
        } else {
            off[j] = o;
            fsrc[j] = isA ? imgF : txtF;
        }
    }

    f4v acc[17];
#pragma unroll
    for (int i = 0; i < 17; ++i) acc[i] = (f4v){0.f, 0.f, 0.f, 0.f};

    const f16x8* frags = (const f16x8*)lds;

    // ---- K loop: 8 steps of BK=64, m97 2-barrier structure ----
#pragma unroll 1
    for (int kc = 0; kc < 8; ++kc) {
        const int k0 = kc * 64;
        if constexpr (PRE) {
#pragma unroll
            for (int j = 0; j < 9; ++j)
                gload_lds16(h16 + off[j] + k0, lds + (4 * j + wave) * 512);
        } else {
#pragma unroll
            for (int j = 0; j < 9; ++j) {
                float4 v0 = *(const float4*)(fsrc[j] + off[j] + k0);
                float4 v1 = *(const float4*)(fsrc[j] + off[j] + k0 + 4);
                union { f16x8 f; uint4 u; } o;
                o.f[0] = (_Float16)v0.x; o.f[1] = (_Float16)v0.y;
                o.f[2] = (_Float16)v0.z; o.f[3] = (_Float16)v0.w;
                o.f[4] = (_Float16)v1.x; o.f[5] = (_Float16)v1.y;
                o.f[6] = (_Float16)v1.z; o.f[7] = (_Float16)v1.w;
                ((uint4*)lds)[(4 * j + wave) * 64 + lane] = o.u;
            }
        }
        __syncthreads();   // staging visible (drains vmcnt/lgkm)
        if (wave == 0) {
            compute_sub<0, 16>(frags, acc, lane);
            compute_sub<0, 16>(frags + 18 * 64, acc, lane);
        } else if (wave == 1) {
            compute_sub<16, 32>(frags, acc, lane);
            compute_sub<16, 32>(frags + 18 * 64, acc, lane);
        } else if (wave == 2) {
            compute_sub<32, 48>(frags, acc, lane);
            compute_sub<32, 48>(frags + 18 * 64, acc, lane);
        } else {
            compute_sub<48, 65>(frags, acc, lane);
            compute_sub<48, 65>(frags + 18 * 64, acc, lane);
        }
        __syncthreads();   // frag reads done before next overwrite
    }

    // ---- fused reductions (LDS re-used as scratch) ----
    for (int i = tid; i < 832; i += 256) rp[i] = -INFINITY;
    __syncthreads();
    if (wave == 0)      reduce_phase1<0, 16>(acc, wave, lq, lm, rp, cp);
    else if (wave == 1) reduce_phase1<16, 32>(acc, wave, lq, lm, rp, cp);
    else if (wave == 2) reduce_phase1<32, 48>(acc, wave, lq, lm, rp, cp);
    else                reduce_phase1<48, 65>(acc, wave, lq, lm, rp, cp);
    __syncthreads();

    float v = 0.f;
    if (tid < N1) {
        int s = tid >> 4, r = tid & 15;
        float m = rp[s * 64 + r];
        m = fmaxf(m, rp[s * 64 + 16 + r]);
        m = fmaxf(m, rp[s * 64 + 32 + r]);
        m = fmaxf(m, rp[s * 64 + 48 + r]);
        v = m;
    }
    v += __shfl_xor(v, 1);  v += __shfl_xor(v, 2);  v += __shfl_xor(v, 4);
    v += __shfl_xor(v, 8);  v += __shfl_xor(v, 16); v += __shfl_xor(v, 32);
    float cv = 0.f;
    if (tid < N2) {
        cv = fmaxf(fmaxf(cp[tid * 4 + 0], cp[tid * 4 + 1]),
                   fmaxf(cp[tid * 4 + 2], cp[tid * 4 + 3]));
    }
    cv += __shfl_xor(cv, 1);  cv += __shfl_xor(cv, 2);  cv += __shfl_xor(cv, 4);
    cv += __shfl_xor(cv, 8);  cv += __shfl_xor(cv, 16); cv += __shfl_xor(cv, 32);
    if (lane == 0) { sws[wave] = v; sws[4 + wave] = cv; }
    __syncthreads();
    if (tid == 0)
        i2t[bi * BB + bt] = (sws[0] + sws[1] + sws[2] + sws[3]) * (1.f / (float)N1);
    if (tid == 1)
        t2i[bt * BB + bi] = (sws[4] + sws[5] + sws[6] + sws[7]) * (1.f / (float)N2);
}

// CE with arange labels over both [B,B] logit matrices.
__global__ __launch_bounds__(256) void ce_kernel(
    const float* __restrict__ i2t, const float* __restrict__ t2i,
    float* __restrict__ out)
{
    const int tid = threadIdx.x;
    const int wid = tid >> 6;
    const int lane = tid & 63;

    float contrib = 0.f;
    if (tid < 2 * BB) {
        const float* M = (tid < BB) ? i2t : t2i;
        const int b = (tid < BB) ? tid : tid - BB;
        const float* row = M + b * BB;
        float mx = row[0];
#pragma unroll 1
        for (int c = 1; c < BB; ++c) mx = fmaxf(mx, row[c]);
        float s = 0.f;
#pragma unroll 1
        for (int c = 0; c < BB; ++c) s += expf(row[c] - mx);
        float lse = mx + logf(s);
        contrib = row[b] - lse;
    }
    contrib += __shfl_xor(contrib, 1);
    contrib += __shfl_xor(contrib, 2);
    contrib += __shfl_xor(contrib, 4);
    contrib += __shfl_xor(contrib, 8);
    contrib += __shfl_xor(contrib, 16);
    contrib += __shfl_xor(contrib, 32);

    __shared__ float s_part[4];
    if (lane == 0) s_part[wid] = contrib;
    __syncthreads();
    if (tid == 0) {
        float total = s_part[0] + s_part[1] + s_part[2] + s_part[3];
        out[0] = -total * (1.f / (float)(2 * BB));
    }
}

extern "C" void kernel_launch(void* const* d_in, const int* in_sizes, int n_in,
                              void* d_out, int out_size, void* d_ws, size_t ws_size,
                              hipStream_t stream) {
    const float* img = (const float*)d_in[0];   // [96,196,512] fp32
    const float* txt = (const float*)d_in[1];   // [96,77,512] fp32
    float* i2t = (float*)d_ws;                  // [96,96]
    float* t2i = i2t + BB * BB;                 // [96,96]

    const size_t conv_off = 2 * BB * BB * sizeof(float);   // 16B-aligned
    const size_t need = conv_off + (size_t)(IMGN + TXTN) * sizeof(_Float16);

    dim3 grid(BB, BB);
    if (ws_size >= need) {
        _Float16* h16 = (_Float16*)((char*)d_ws + conv_off);
        convert_kernel<<<(IMGN / 4 + 255) / 256, 256, 0, stream>>>(img, h16, IMGN);
        convert_kernel<<<(TXTN / 4 + 255) / 256, 256, 0, stream>>>(txt, h16 + IMGN, TXTN);
        sim_mfma_kernel<true><<<grid, 256, 0, stream>>>(img, txt, h16, i2t, t2i);
    } else {
        sim_mfma_kernel<false><<<grid, 256, 0, stream>>>(img, txt, nullptr, i2t, t2i);
    }
    ce_kernel<<<1, 256, 0, stream>>>(i2t, t2i, (float*)d_out);
}

// Round 6
// 479.894 us; speedup vs baseline: 3.1506x; 3.1506x over previous
//
#include <hip/hip_runtime.h>
#include <math.h>

// FineGrainLoss: B=96, n1=196 (image tokens), n2=77 (text tokens), d=512.
#define BB 96
#define N1 196
#define N2 77
#define DD 512

#define MT 13   // M tiles of 16 (208 rows, 196 valid)
#define NT 5    // N tiles of 16 (80 cols, 77 valid)

#define IMGN (BB * N1 * DD)
#define TXTN (BB * N2 * DD)

// BK=64 staging: 36 tiles of 64 cells (16 B each = 8 f16 frag slice).
// Tile map: T in [0,36): sub = T/18; T'=T%18; T'<13 -> A strip T'; else B ct T'-13.
#define TILES 36
#define CELLS (TILES * 64)   // 2304 = 9*256

typedef _Float16 f16x8 __attribute__((ext_vector_type(8)));  // 8 f16 (4 VGPR)
typedef float f4v __attribute__((ext_vector_type(4)));       // MFMA C/D

typedef unsigned int __attribute__((address_space(1))) as1_uint;
typedef unsigned int __attribute__((address_space(3))) as3_uint;

__device__ __forceinline__ void gload_lds16(const void* g, void* l) {
    __builtin_amdgcn_global_load_lds((const as1_uint*)g, (as3_uint*)l, 16, 0, 0);
}

// fp32 -> fp16 convert pass (4 elems/thread).
__global__ void convert_kernel(const float* __restrict__ src,
                               _Float16* __restrict__ dst, int n) {
    int i = (blockIdx.x * blockDim.x + threadIdx.x) * 4;
    if (i >= n) return;
    float4 v = *(const float4*)(src + i);
    union { _Float16 h[4]; uint2 u; } o;
    o.h[0] = (_Float16)v.x; o.h[1] = (_Float16)v.y;
    o.h[2] = (_Float16)v.z; o.h[3] = (_Float16)v.w;
    *(uint2*)(dst + i) = o.u;
}

// One K=32 sub-step for wave units [U0,U1), strip-major u = strip*NT + ct.
template <int U0, int U1>
__device__ __forceinline__ void compute_sub(const f16x8* __restrict__ fr,
                                            f4v* __restrict__ acc, int lane) {
    constexpr int S0 = U0 / NT, S1 = (U1 - 1) / NT, NS = S1 - S0 + 1;
    f16x8 bh[NT];
#pragma unroll
    for (int ct = 0; ct < NT; ++ct) bh[ct] = fr[(13 + ct) * 64 + lane];
#pragma unroll
    for (int i = 0; i < NS; ++i) {
        const int s = S0 + i;
        f16x8 ah = fr[s * 64 + lane];
#pragma unroll
        for (int ct = 0; ct < NT; ++ct) {
            const int u = s * NT + ct;
            if (u >= U0 && u < U1)
                acc[u - U0] = __builtin_amdgcn_mfma_f32_16x16x32_f16(
                    ah, bh[ct], acc[u - U0], 0, 0, 0);
        }
    }
}

// Per-wave reduction partials. C/D layout: col = lane&15, row = (lane>>4)*4+reg.
// rp: [13 strips][4 waves][16 rows], cp: [80 cols][4 waves].
template <int U0, int U1>
__device__ __forceinline__ void reduce_phase1(const f4v* __restrict__ acc, int wave,
                                              int lq, int lm,
                                              float* __restrict__ rp,
                                              float* __restrict__ cp) {
    constexpr int S0 = U0 / NT, S1 = (U1 - 1) / NT, NS = S1 - S0 + 1;
    float colm[NT];
#pragma unroll
    for (int ct = 0; ct < NT; ++ct) colm[ct] = -INFINITY;
    float rowm[NS][4];
#pragma unroll
    for (int i = 0; i < NS; ++i)
#pragma unroll
        for (int r = 0; r < 4; ++r) rowm[i][r] = -INFINITY;

#pragma unroll
    for (int u = U0; u < U1; ++u) {
        const int s = u / NT, ct = u % NT;
        f4v a = acc[u - U0];
        bool rows_ok = (s != MT - 1) || (lq == 0);        // rows >=196 invalid
        float cm = fmaxf(fmaxf(a[0], a[1]), fmaxf(a[2], a[3]));
        colm[ct] = fmaxf(colm[ct], rows_ok ? cm : -INFINITY);
        bool col_ok = (ct != NT - 1) || (lm < N2 - 64);   // cols >=77 invalid
#pragma unroll
        for (int r = 0; r < 4; ++r)
            rowm[s - S0][r] = fmaxf(rowm[s - S0][r], col_ok ? a[r] : -INFINITY);
    }
#pragma unroll
    for (int ct = 0; ct < NT; ++ct) {
        float m = colm[ct];
        m = fmaxf(m, __shfl_xor(m, 16));
        m = fmaxf(m, __shfl_xor(m, 32));
        if (lq == 0) cp[(ct * 16 + lm) * 4 + wave] = m;
    }
#pragma unroll
    for (int i = 0; i < NS; ++i) {
#pragma unroll
        for (int r = 0; r < 4; ++r) {
            float m = rowm[i][r];
            m = fmaxf(m, __shfl_xor(m, 1));
            m = fmaxf(m, __shfl_xor(m, 2));
            m = fmaxf(m, __shfl_xor(m, 4));
            m = fmaxf(m, __shfl_xor(m, 8));
            if (lm == 0) rp[(S0 + i) * 64 + wave * 16 + lq * 4 + r] = m;
        }
    }
}

// One block per (bi, bt): S[208x80] = img[bi].txt[bt]^T, single f16 MFMA,
// BK=64 global_load_lds staging (m97 structure), fused max/mean epilogue.
// __launch_bounds__(256,2): VGPR cap 256 — acc[17] (68 f32) MUST stay in
// registers; (256,4) in R5 capped at 128 and spilled acc to scratch
// (WRITE_SIZE 4.2 GB, 2x slower). Do not raise the min-waves arg.
template <bool PRE>
__global__ __launch_bounds__(256, 2) void sim_mfma_kernel(
    const float* __restrict__ imgF, const float* __restrict__ txtF,
    const _Float16* __restrict__ h16,   // [img | txt] concatenated
    float* __restrict__ i2t, float* __restrict__ t2i)
{
    const int bt = blockIdx.x, bi = blockIdx.y;
    const int tid = threadIdx.x;
    const int wave = tid >> 6, lane = tid & 63;
    const int lm = lane & 15;
    const int lq = lane >> 4;

    __shared__ __align__(16) _Float16 lds[CELLS * 8];   // 36,864 B
    // epilogue scratch aliases the staging tile (K loop fully done first)
    float* rp  = (float*)lds;          // 832: [strip][wave][16]
    float* cp  = (float*)lds + 832;    // 320: [col][wave]
    float* sws = (float*)lds + 1152;   // 8

    // ---- per-thread staging descriptors (k-invariant element offsets) ----
    // Thread stages cells of tile T = 4j + wave, cell-in-tile = lane.
    int off[9];
    const float* fsrc[9];
#pragma unroll
    for (int j = 0; j < 9; ++j) {
        const int T = 4 * j + wave;
        const int sub = T / 18, Tp = T % 18;
        const int kb = lq;   // k-block within K32
        int o;
        bool isA = (Tp < 13);
        if (isA) {
            int q = Tp * 16 + lm; q = q > (N1 - 1) ? (N1 - 1) : q;
            o = (bi * N1 + q) * DD + sub * 32 + kb * 8;
        } else {
            int r = (Tp - 13) * 16 + lm; r = r > (N2 - 1) ? (N2 - 1) : r;
            o = (bt * N2 + r) * DD + sub * 32 + kb * 8;
        }
        if constexpr (PRE) {
            off[j] = isA ? o : (IMGN + o);
        } else {
            off[j] = o;
            fsrc[j] = isA ? imgF : txtF;
        }
    }

    f4v acc[17];
#pragma unroll
    for (int i = 0; i < 17; ++i) acc[i] = (f4v){0.f, 0.f, 0.f, 0.f};

    const f16x8* frags = (const f16x8*)lds;

    // ---- K loop: 8 steps of BK=64, m97 2-barrier structure ----
#pragma unroll 1
    for (int kc = 0; kc < 8; ++kc) {
        const int k0 = kc * 64;
        if constexpr (PRE) {
#pragma unroll
            for (int j = 0; j < 9; ++j)
                gload_lds16(h16 + off[j] + k0, lds + (4 * j + wave) * 512);
        } else {
#pragma unroll
            for (int j = 0; j < 9; ++j) {
                float4 v0 = *(const float4*)(fsrc[j] + off[j] + k0);
                float4 v1 = *(const float4*)(fsrc[j] + off[j] + k0 + 4);
                union { f16x8 f; uint4 u; } o;
                o.f[0] = (_Float16)v0.x; o.f[1] = (_Float16)v0.y;
                o.f[2] = (_Float16)v0.z; o.f[3] = (_Float16)v0.w;
                o.f[4] = (_Float16)v1.x; o.f[5] = (_Float16)v1.y;
                o.f[6] = (_Float16)v1.z; o.f[7] = (_Float16)v1.w;
                ((uint4*)lds)[(4 * j + wave) * 64 + lane] = o.u;
            }
        }
        __syncthreads();   // staging visible (drains vmcnt/lgkm)
        if (wave == 0) {
            compute_sub<0, 16>(frags, acc, lane);
            compute_sub<0, 16>(frags + 18 * 64, acc, lane);
        } else if (wave == 1) {
            compute_sub<16, 32>(frags, acc, lane);
            compute_sub<16, 32>(frags + 18 * 64, acc, lane);
        } else if (wave == 2) {
            compute_sub<32, 48>(frags, acc, lane);
            compute_sub<32, 48>(frags + 18 * 64, acc, lane);
        } else {
            compute_sub<48, 65>(frags, acc, lane);
            compute_sub<48, 65>(frags + 18 * 64, acc, lane);
        }
        __syncthreads();   // frag reads done before next overwrite
    }

    // ---- fused reductions (LDS re-used as scratch) ----
    for (int i = tid; i < 832; i += 256) rp[i] = -INFINITY;
    __syncthreads();
    if (wave == 0)      reduce_phase1<0, 16>(acc, wave, lq, lm, rp, cp);
    else if (wave == 1) reduce_phase1<16, 32>(acc, wave, lq, lm, rp, cp);
    else if (wave == 2) reduce_phase1<32, 48>(acc, wave, lq, lm, rp, cp);
    else                reduce_phase1<48, 65>(acc, wave, lq, lm, rp, cp);
    __syncthreads();

    float v = 0.f;
    if (tid < N1) {
        int s = tid >> 4, r = tid & 15;
        float m = rp[s * 64 + r];
        m = fmaxf(m, rp[s * 64 + 16 + r]);
        m = fmaxf(m, rp[s * 64 + 32 + r]);
        m = fmaxf(m, rp[s * 64 + 48 + r]);
        v = m;
    }
    v += __shfl_xor(v, 1);  v += __shfl_xor(v, 2);  v += __shfl_xor(v, 4);
    v += __shfl_xor(v, 8);  v += __shfl_xor(v, 16); v += __shfl_xor(v, 32);
    float cv = 0.f;
    if (tid < N2) {
        cv = fmaxf(fmaxf(cp[tid * 4 + 0], cp[tid * 4 + 1]),
                   fmaxf(cp[tid * 4 + 2], cp[tid * 4 + 3]));
    }
    cv += __shfl_xor(cv, 1);  cv += __shfl_xor(cv, 2);  cv += __shfl_xor(cv, 4);
    cv += __shfl_xor(cv, 8);  cv += __shfl_xor(cv, 16); cv += __shfl_xor(cv, 32);
    if (lane == 0) { sws[wave] = v; sws[4 + wave] = cv; }
    __syncthreads();
    if (tid == 0)
        i2t[bi * BB + bt] = (sws[0] + sws[1] + sws[2] + sws[3]) * (1.f / (float)N1);
    if (tid == 1)
        t2i[bt * BB + bi] = (sws[4] + sws[5] + sws[6] + sws[7]) * (1.f / (float)N2);
}

// CE with arange labels over both [B,B] logit matrices.
__global__ __launch_bounds__(256) void ce_kernel(
    const float* __restrict__ i2t, const float* __restrict__ t2i,
    float* __restrict__ out)
{
    const int tid = threadIdx.x;
    const int wid = tid >> 6;
    const int lane = tid & 63;

    float contrib = 0.f;
    if (tid < 2 * BB) {
        const float* M = (tid < BB) ? i2t : t2i;
        const int b = (tid < BB) ? tid : tid - BB;
        const float* row = M + b * BB;
        float mx = row[0];
#pragma unroll 1
        for (int c = 1; c < BB; ++c) mx = fmaxf(mx, row[c]);
        float s = 0.f;
#pragma unroll 1
        for (int c = 0; c < BB; ++c) s += expf(row[c] - mx);
        float lse = mx + logf(s);
        contrib = row[b] - lse;
    }
    contrib += __shfl_xor(contrib, 1);
    contrib += __shfl_xor(contrib, 2);
    contrib += __shfl_xor(contrib, 4);
    contrib += __shfl_xor(contrib, 8);
    contrib += __shfl_xor(contrib, 16);
    contrib += __shfl_xor(contrib, 32);

    __shared__ float s_part[4];
    if (lane == 0) s_part[wid] = contrib;
    __syncthreads();
    if (tid == 0) {
        float total = s_part[0] + s_part[1] + s_part[2] + s_part[3];
        out[0] = -total * (1.f / (float)(2 * BB));
    }
}

extern "C" void kernel_launch(void* const* d_in, const int* in_sizes, int n_in,
                              void* d_out, int out_size, void* d_ws, size_t ws_size,
                              hipStream_t stream) {
    const float* img = (const float*)d_in[0];   // [96,196,512] fp32
    const float* txt = (const float*)d_in[1];   // [96,77,512] fp32
    float* i2t = (float*)d_ws;                  // [96,96]
    float* t2i = i2t + BB * BB;                 // [96,96]

    const size_t conv_off = 2 * BB * BB * sizeof(float);   // 16B-aligned
    const size_t need = conv_off + (size_t)(IMGN + TXTN) * sizeof(_Float16);

    dim3 grid(BB, BB);
    if (ws_size >= need) {
        _Float16* h16 = (_Float16*)((char*)d_ws + conv_off);
        convert_kernel<<<(IMGN / 4 + 255) / 256, 256, 0, stream>>>(img, h16, IMGN);
        convert_kernel<<<(TXTN / 4 + 255) / 256, 256, 0, stream>>>(txt, h16 + IMGN, TXTN);
        sim_mfma_kernel<true><<<grid, 256, 0, stream>>>(img, txt, h16, i2t, t2i);
    } else {
        sim_mfma_kernel<false><<<grid, 256, 0, stream>>>(img, txt, nullptr, i2t, t2i);
    }
    ce_kernel<<<1, 256, 0, stream>>>(i2t, t2i, (float*)d_out);
}

// Round 7
// 477.704 us; speedup vs baseline: 3.1651x; 1.0046x over previous
//
#include <hip/hip_runtime.h>
#include <math.h>

// FineGrainLoss: B=96, n1=196 (image tokens), n2=77 (text tokens), d=512.
#define BB 96
#define N1 196
#define N2 77
#define DD 512

#define NT 5    // N tiles of 16 (80 cols, 77 valid)

#define IMGN (BB * N1 * DD)
#define TXTN (BB * N2 * DD)

// M-split: blockIdx.z = MH. MH0: strips 0-6 (35 units), MH1: strips 7-12
// (30 units; staged strip 13 is clamp-padding, never computed).
// Per K=64 step: 2 subs x (7 A + 5 B) tiles x 64 cells x 16 B = 24,576 B.
#define TILES 24
#define CELLS (TILES * 64)   // 1536 = 6*256

typedef _Float16 f16x8 __attribute__((ext_vector_type(8)));  // 8 f16 (4 VGPR)
typedef float f4v __attribute__((ext_vector_type(4)));       // MFMA C/D

typedef unsigned int __attribute__((address_space(1))) as1_uint;
typedef unsigned int __attribute__((address_space(3))) as3_uint;

__device__ __forceinline__ void gload_lds16(const void* g, void* l) {
    __builtin_amdgcn_global_load_lds((const as1_uint*)g, (as3_uint*)l, 16, 0, 0);
}

// fp32 -> fp16 convert pass (4 elems/thread).
__global__ void convert_kernel(const float* __restrict__ src,
                               _Float16* __restrict__ dst, int n) {
    int i = (blockIdx.x * blockDim.x + threadIdx.x) * 4;
    if (i >= n) return;
    float4 v = *(const float4*)(src + i);
    union { _Float16 h[4]; uint2 u; } o;
    o.h[0] = (_Float16)v.x; o.h[1] = (_Float16)v.y;
    o.h[2] = (_Float16)v.z; o.h[3] = (_Float16)v.w;
    *(uint2*)(dst + i) = o.u;
}

// One K=32 sub-step for wave units [U0,U1), strip-major u = s_local*NT + ct.
// A strip s at tile s (0-6), B ct at tile 7+ct.
template <int U0, int U1>
__device__ __forceinline__ void compute_sub(const f16x8* __restrict__ fr,
                                            f4v* __restrict__ acc, int lane) {
    constexpr int S0 = U0 / NT, S1 = (U1 - 1) / NT, NS = S1 - S0 + 1;
    f16x8 bh[NT];
#pragma unroll
    for (int ct = 0; ct < NT; ++ct) bh[ct] = fr[(7 + ct) * 64 + lane];
#pragma unroll
    for (int i = 0; i < NS; ++i) {
        const int s = S0 + i;
        f16x8 ah = fr[s * 64 + lane];
#pragma unroll
        for (int ct = 0; ct < NT; ++ct) {
            const int u = s * NT + ct;
            if (u >= U0 && u < U1)
                acc[u - U0] = __builtin_amdgcn_mfma_f32_16x16x32_f16(
                    ah, bh[ct], acc[u - U0], 0, 0, 0);
        }
    }
}

// Per-wave reduction partials. C/D layout: col = lane&15, row = (lane>>4)*4+reg.
// rp: [7 strips][4 waves][16 rows], cp: [80 cols][4 waves]. BS = global strip base.
template <int U0, int U1>
__device__ __forceinline__ void reduce_phase1(const f4v* __restrict__ acc, int wave,
                                              int lq, int lm, int BS,
                                              float* __restrict__ rp,
                                              float* __restrict__ cp) {
    constexpr int S0 = U0 / NT, S1 = (U1 - 1) / NT, NS = S1 - S0 + 1;
    float colm[NT];
#pragma unroll
    for (int ct = 0; ct < NT; ++ct) colm[ct] = -INFINITY;
    float rowm[NS][4];
#pragma unroll
    for (int i = 0; i < NS; ++i)
#pragma unroll
        for (int r = 0; r < 4; ++r) rowm[i][r] = -INFINITY;

#pragma unroll
    for (int u = U0; u < U1; ++u) {
        const int s = u / NT, ct = u % NT;
        f4v a = acc[u - U0];
        // rows q = (BS+s)*16 + lq*4 + reg; invalid iff global strip 12 && lq>0
        bool rows_ok = ((BS + s) != 12) || (lq == 0);
        float cm = fmaxf(fmaxf(a[0], a[1]), fmaxf(a[2], a[3]));
        colm[ct] = fmaxf(colm[ct], rows_ok ? cm : -INFINITY);
        bool col_ok = (ct != NT - 1) || (lm < N2 - 64);   // cols >=77 invalid
#pragma unroll
        for (int r = 0; r < 4; ++r)
            rowm[s - S0][r] = fmaxf(rowm[s - S0][r], col_ok ? a[r] : -INFINITY);
    }
#pragma unroll
    for (int ct = 0; ct < NT; ++ct) {
        float m = colm[ct];
        m = fmaxf(m, __shfl_xor(m, 16));
        m = fmaxf(m, __shfl_xor(m, 32));
        if (lq == 0) cp[(ct * 16 + lm) * 4 + wave] = m;
    }
#pragma unroll
    for (int i = 0; i < NS; ++i) {
#pragma unroll
        for (int r = 0; r < 4; ++r) {
            float m = rowm[i][r];
            m = fmaxf(m, __shfl_xor(m, 1));
            m = fmaxf(m, __shfl_xor(m, 2));
            m = fmaxf(m, __shfl_xor(m, 4));
            m = fmaxf(m, __shfl_xor(m, 8));
            if (lm == 0) rp[(S0 + i) * 64 + wave * 16 + lq * 4 + r] = m;
        }
    }
}

// One block per (bi, bt, MH): half-M slice of S = img[bi].txt[bt]^T, single
// f16 MFMA, BK=64 global_load_lds staging (m97 2-barrier structure).
// Writes partials: p_i2t[MH][bi][bt] (rowmax sum), p_col[MH][bi][bt][80].
// __launch_bounds__(256,2): VGPR cap 256 — acc must stay in registers;
// (256,4) in R5 capped at 128 and spilled acc to scratch (4.2 GB writes).
template <bool PRE>
__global__ __launch_bounds__(256, 2) void sim_mfma_kernel(
    const float* __restrict__ imgF, const float* __restrict__ txtF,
    const _Float16* __restrict__ h16,   // [img | txt] concatenated
    float* __restrict__ p_i2t, float* __restrict__ p_col)
{
    const int bt = blockIdx.x, bi = blockIdx.y, MH = blockIdx.z;
    const int BS = MH ? 7 : 0;          // global strip base
    const int tid = threadIdx.x;
    const int wave = tid >> 6, lane = tid & 63;
    const int lm = lane & 15;
    const int lq = lane >> 4;

    __shared__ __align__(16) _Float16 lds[CELLS * 8];   // 24,576 B
    // epilogue scratch aliases the staging tile (K loop fully done first)
    float* rp  = (float*)lds;          // 448: [strip][wave][16]
    float* cp  = (float*)lds + 448;    // 320: [col][wave]
    float* sws = (float*)lds + 768;    // 4

    // ---- per-thread staging descriptors (k-invariant element offsets) ----
    // Thread stages cells of tile T = 4j + wave, cell-in-tile = lane.
    // T: sub = T/12, T' = T%12; T'<7 -> A strip BS+T'; else B ct T'-7.
    int off[6];
    const float* fsrc[6];
#pragma unroll
    for (int j = 0; j < 6; ++j) {
        const int T = 4 * j + wave;
        const int sub = T / 12, Tp = T % 12;
        int o;
        bool isA = (Tp < 7);
        if (isA) {
            int q = (BS + Tp) * 16 + lm; q = q > (N1 - 1) ? (N1 - 1) : q;
            o = (bi * N1 + q) * DD + sub * 32 + lq * 8;
        } else {
            int r = (Tp - 7) * 16 + lm; r = r > (N2 - 1) ? (N2 - 1) : r;
            o = (bt * N2 + r) * DD + sub * 32 + lq * 8;
        }
        if constexpr (PRE) {
            off[j] = isA ? o : (IMGN + o);
        } else {
            off[j] = o;
            fsrc[j] = isA ? imgF : txtF;
        }
    }

    f4v acc[9];
#pragma unroll
    for (int i = 0; i < 9; ++i) acc[i] = (f4v){0.f, 0.f, 0.f, 0.f};

    const f16x8* frags = (const f16x8*)lds;

    auto do_compute = [&](const f16x8* fr) {
        if (MH == 0) {
            if (wave == 0)      compute_sub<0, 9>(fr, acc, lane);
            else if (wave == 1) compute_sub<9, 18>(fr, acc, lane);
            else if (wave == 2) compute_sub<18, 27>(fr, acc, lane);
            else                compute_sub<27, 35>(fr, acc, lane);
        } else {
            if (wave == 0)      compute_sub<0, 8>(fr, acc, lane);
            else if (wave == 1) compute_sub<8, 16>(fr, acc, lane);
            else if (wave == 2) compute_sub<16, 23>(fr, acc, lane);
            else                compute_sub<23, 30>(fr, acc, lane);
        }
    };

    // ---- K loop: 8 steps of BK=64, m97 2-barrier structure ----
#pragma unroll 1
    for (int kc = 0; kc < 8; ++kc) {
        const int k0 = kc * 64;
        if constexpr (PRE) {
#pragma unroll
            for (int j = 0; j < 6; ++j)
                gload_lds16(h16 + off[j] + k0, lds + (4 * j + wave) * 512);
        } else {
#pragma unroll
            for (int j = 0; j < 6; ++j) {
                float4 v0 = *(const float4*)(fsrc[j] + off[j] + k0);
                float4 v1 = *(const float4*)(fsrc[j] + off[j] + k0 + 4);
                union { f16x8 f; uint4 u; } o;
                o.f[0] = (_Float16)v0.x; o.f[1] = (_Float16)v0.y;
                o.f[2] = (_Float16)v0.z; o.f[3] = (_Float16)v0.w;
                o.f[4] = (_Float16)v1.x; o.f[5] = (_Float16)v1.y;
                o.f[6] = (_Float16)v1.z; o.f[7] = (_Float16)v1.w;
                ((uint4*)lds)[(4 * j + wave) * 64 + lane] = o.u;
            }
        }
        __syncthreads();   // staging visible (drains vmcnt/lgkm)
        do_compute(frags);
        do_compute(frags + 12 * 64);
        __syncthreads();   // frag reads done before next overwrite
    }

    // ---- fused reductions (LDS re-used as scratch) ----
    for (int i = tid; i < 448; i += 256) rp[i] = -INFINITY;
    __syncthreads();
    if (MH == 0) {
        if (wave == 0)      reduce_phase1<0, 9>(acc, wave, lq, lm, BS, rp, cp);
        else if (wave == 1) reduce_phase1<9, 18>(acc, wave, lq, lm, BS, rp, cp);
        else if (wave == 2) reduce_phase1<18, 27>(acc, wave, lq, lm, BS, rp, cp);
        else                reduce_phase1<27, 35>(acc, wave, lq, lm, BS, rp, cp);
    } else {
        if (wave == 0)      reduce_phase1<0, 8>(acc, wave, lq, lm, BS, rp, cp);
        else if (wave == 1) reduce_phase1<8, 16>(acc, wave, lq, lm, BS, rp, cp);
        else if (wave == 2) reduce_phase1<16, 23>(acc, wave, lq, lm, BS, rp, cp);
        else                reduce_phase1<23, 30>(acc, wave, lq, lm, BS, rp, cp);
    }
    __syncthreads();

    // rowmax sum over this block's valid rows (MH0: 112 rows; MH1: 84 of 96)
    const int NROWS = MH ? 84 : 112;
    float v = 0.f;
    if (tid < NROWS) {
        int s = tid >> 4, r = tid & 15;
        float m = rp[s * 64 + r];
        m = fmaxf(m, rp[s * 64 + 16 + r]);
        m = fmaxf(m, rp[s * 64 + 32 + r]);
        m = fmaxf(m, rp[s * 64 + 48 + r]);
        v = m;
    }
    v += __shfl_xor(v, 1);  v += __shfl_xor(v, 2);  v += __shfl_xor(v, 4);
    v += __shfl_xor(v, 8);  v += __shfl_xor(v, 16); v += __shfl_xor(v, 32);
    if (lane == 0) sws[wave] = v;
    __syncthreads();
    if (tid == 0)
        p_i2t[(MH * BB + bi) * BB + bt] = sws[0] + sws[1] + sws[2] + sws[3];
    if (tid < 80) {
        float cv = fmaxf(fmaxf(cp[tid * 4 + 0], cp[tid * 4 + 1]),
                         fmaxf(cp[tid * 4 + 2], cp[tid * 4 + 3]));
        p_col[(size_t)((MH * BB + bi) * BB + bt) * 80 + tid] = cv;
    }
}

// Merge M-half partials: i2t = (p0+p1)/196; t2i = mean_r max(c0[r], c1[r]).
__global__ __launch_bounds__(64) void combine_kernel(
    const float* __restrict__ p_i2t, const float* __restrict__ p_col,
    float* __restrict__ i2t, float* __restrict__ t2i)
{
    const int bt = blockIdx.x, bi = blockIdx.y, tid = threadIdx.x;
    const float* c0 = p_col + (size_t)(bi * BB + bt) * 80;
    const float* c1 = p_col + (size_t)((BB + bi) * BB + bt) * 80;
    float v = fmaxf(c0[tid], c1[tid]);              // r = tid (0..63, all <77)
    if (tid < N2 - 64) v += fmaxf(c0[tid + 64], c1[tid + 64]);
    v += __shfl_xor(v, 1);  v += __shfl_xor(v, 2);  v += __shfl_xor(v, 4);
    v += __shfl_xor(v, 8);  v += __shfl_xor(v, 16); v += __shfl_xor(v, 32);
    if (tid == 0) {
        t2i[bt * BB + bi] = v * (1.f / (float)N2);
        i2t[bi * BB + bt] = (p_i2t[bi * BB + bt] + p_i2t[(BB + bi) * BB + bt])
                            * (1.f / (float)N1);
    }
}

// CE with arange labels over both [B,B] logit matrices.
__global__ __launch_bounds__(256) void ce_kernel(
    const float* __restrict__ i2t, const float* __restrict__ t2i,
    float* __restrict__ out)
{
    const int tid = threadIdx.x;
    const int wid = tid >> 6;
    const int lane = tid & 63;

    float contrib = 0.f;
    if (tid < 2 * BB) {
        const float* M = (tid < BB) ? i2t : t2i;
        const int b = (tid < BB) ? tid : tid - BB;
        const float* row = M + b * BB;
        float mx = row[0];
#pragma unroll 1
        for (int c = 1; c < BB; ++c) mx = fmaxf(mx, row[c]);
        float s = 0.f;
#pragma unroll 1
        for (int c = 0; c < BB; ++c) s += expf(row[c] - mx);
        float lse = mx + logf(s);
        contrib = row[b] - lse;
    }
    contrib += __shfl_xor(contrib, 1);
    contrib += __shfl_xor(contrib, 2);
    contrib += __shfl_xor(contrib, 4);
    contrib += __shfl_xor(contrib, 8);
    contrib += __shfl_xor(contrib, 16);
    contrib += __shfl_xor(contrib, 32);

    __shared__ float s_part[4];
    if (lane == 0) s_part[wid] = contrib;
    __syncthreads();
    if (tid == 0) {
        float total = s_part[0] + s_part[1] + s_part[2] + s_part[3];
        out[0] = -total * (1.f / (float)(2 * BB));
    }
}

extern "C" void kernel_launch(void* const* d_in, const int* in_sizes, int n_in,
                              void* d_out, int out_size, void* d_ws, size_t ws_size,
                              hipStream_t stream) {
    const float* img = (const float*)d_in[0];   // [96,196,512] fp32
    const float* txt = (const float*)d_in[1];   // [96,77,512] fp32

    // ws layout (floats): i2t[9216] | t2i[9216] | p_i2t[2*9216] |
    //                     p_col[2*9216*80] | h16 (f16, 16B-aligned)
    float* i2t   = (float*)d_ws;
    float* t2i   = i2t + BB * BB;
    float* p_i2t = t2i + BB * BB;
    float* p_col = p_i2t + 2 * BB * BB;
    const size_t conv_off = (size_t)(4 + 2 * 80) * BB * BB * sizeof(float);
    const size_t need = conv_off + (size_t)(IMGN + TXTN) * sizeof(_Float16);

    dim3 grid(BB, BB, 2);
    dim3 cgrid(BB, BB);
    if (ws_size >= need) {
        _Float16* h16 = (_Float16*)((char*)d_ws + conv_off);
        convert_kernel<<<(IMGN / 4 + 255) / 256, 256, 0, stream>>>(img, h16, IMGN);
        convert_kernel<<<(TXTN / 4 + 255) / 256, 256, 0, stream>>>(txt, h16 + IMGN, TXTN);
        sim_mfma_kernel<true><<<grid, 256, 0, stream>>>(img, txt, h16, p_i2t, p_col);
    } else {
        sim_mfma_kernel<false><<<grid, 256, 0, stream>>>(img, txt, nullptr, p_i2t, p_col);
    }
    combine_kernel<<<cgrid, 64, 0, stream>>>(p_i2t, p_col, i2t, t2i);
    ce_kernel<<<1, 256, 0, stream>>>(i2t, t2i, (float*)d_out);
}